// Round 8
// baseline (199.552 us; speedup 1.0000x reference)
//
#include <hip/hip_runtime.h>

#define DIM 1024
#define NH 8
#define HD 128
#define T_SEQ 2048
#define NTOK 8192
#define QKV_N 3072
#define ATTN_SCALE 0.12f
#define RMS_EPS 1.1920929e-07f

using f32x4  = __attribute__((ext_vector_type(4))) float;
using bf16x8 = __attribute__((ext_vector_type(8))) __bf16;

__device__ __forceinline__ unsigned short f2bf(float f) {
    unsigned int u = __builtin_bit_cast(unsigned int, f);
    u += 0x7fffu + ((u >> 16) & 1u);           // RNE
    return (unsigned short)(u >> 16);
}
__device__ __forceinline__ float bf2f(unsigned short s) {
    unsigned int u = ((unsigned int)s) << 16;
    return __builtin_bit_cast(float, u);
}
__device__ __forceinline__ unsigned int cvtpk(float lo, float hi) {
    unsigned int r;
    asm("v_cvt_pk_bf16_f32 %0, %1, %2" : "=v"(r) : "v"(lo), "v"(hi));
    return r;
}

// async global->LDS, 16B/lane; LDS dest = wave-uniform base + lane*16 (HW)
__device__ __forceinline__ void gll16(const void* g, void* l) {
    __builtin_amdgcn_global_load_lds(
        (const __attribute__((address_space(1))) unsigned int*)g,
        (__attribute__((address_space(3))) unsigned int*)l, 16, 0, 0);
}

#define VMCNT(n) asm volatile("s_waitcnt vmcnt(" #n ")" ::: "memory")

// ---------------------------------------------------------------- prep: all f32->bf16 conversions + RoPE table, one launch
__global__ __launch_bounds__(256) void prep(const float* __restrict__ x,
                                            const float* __restrict__ qkvw,
                                            const float* __restrict__ cprojw,
                                            unsigned short* __restrict__ xb,
                                            unsigned short* __restrict__ wqb,
                                            unsigned short* __restrict__ cpb,
                                            float2* __restrict__ tab) {
    const int bid = blockIdx.x;
    const int tid = threadIdx.x;
    if (bid < 12288) {
        const float* in;
        unsigned short* out;
        int i;
        if (bid < 8192)        { in = x;      out = xb;  i = bid*256 + tid; }
        else if (bid < 11264)  { in = qkvw;   out = wqb; i = (bid-8192)*256 + tid; }
        else                   { in = cprojw; out = cpb; i = (bid-11264)*256 + tid; }
        float4 f = ((const float4*)in)[i];
        ushort4 o;
        o.x = f2bf(f.x); o.y = f2bf(f.y); o.z = f2bf(f.z); o.w = f2bf(f.w);
        ((ushort4*)out)[i] = o;
    } else {
        int idx = (bid - 12288)*256 + tid;    // < 65536
        int t = idx >> 5, i = idx & 31;
        float th = (float)t * exp2f((float)i * (-10.0f/31.0f));
        float sn, cs;
        sincosf(th, &sn, &cs);
        tab[idx] = make_float2(cs, sn);
    }
}

#define SLOT_A 32768
#define SLOT_SZ 49152

// ---------------------------------------------------------------- fused QKV GEMM (256x128 ring-3) + RMSNorm/RoPE/vmix epilogue
// N-tile == one head-slice: htyp = n0/128: 0-7 q-head, 8-15 k-head, 16-23 v-head.
// M-tile (256 tokens) never straddles a batch boundary (2048 % 256 == 0).
__global__ __launch_bounds__(512, 1) void gemm_qkv(const unsigned short* __restrict__ A,
                                                   const unsigned short* __restrict__ B,
                                                   const float* __restrict__ ve,
                                                   const float* __restrict__ lam,
                                                   const float2* __restrict__ tab,
                                                   unsigned short* __restrict__ qa,
                                                   unsigned short* __restrict__ ka,
                                                   unsigned short* __restrict__ vt,
                                                   int M, int N, int K, int nbn) {
    __shared__ __align__(16) char smem[147456];
    const int tid  = threadIdx.x;
    const int lane = tid & 63;
    const int w    = tid >> 6;
    const int wm   = w >> 1, wn = w & 1;
    const int lr   = lane & 15, lg = lane >> 4;
    const int xsw  = (lr & 7) << 3;

    const int chunk = gridDim.x >> 3;
    const int bid2  = (blockIdx.x & 7) * chunk + (blockIdx.x >> 3);
    const int m0 = (bid2 / nbn) * 256;
    const int n0 = (bid2 % nbn) * 128;

    const int rsub = lane >> 3;
    const int csw  = ((lane & 7) ^ rsub) << 3;

    char* s0 = smem;
    char* s1 = smem + SLOT_SZ;
    char* s2 = smem + 2*SLOT_SZ;

    auto stage = [&](int kt, char* slot) {
        const int kb = kt * 64;
        #pragma unroll
        for (int i = 0; i < 4; ++i) {
            int c = w*4 + i;
            gll16(&A[(size_t)(m0 + c*8 + rsub)*K + kb + csw], slot + c*1024);
        }
        #pragma unroll
        for (int i = 0; i < 2; ++i) {
            int c = w*2 + i;
            gll16(&B[(size_t)(n0 + c*8 + rsub)*K + kb + csw], slot + SLOT_A + c*1024);
        }
    };

    f32x4 acc[4][4] = {};
    const int KT = K / 64;

    stage(0, s0);
    stage(1, s1);
    VMCNT(6);
    __builtin_amdgcn_s_barrier();
    __builtin_amdgcn_sched_barrier(0);

    for (int t = 0; t < KT; ++t) {
        if (t + 2 < KT) stage(t + 2, s2);
        const unsigned short* sA = (const unsigned short*)s0;
        const unsigned short* sB = (const unsigned short*)(s0 + SLOT_A);
        bf16x8 bfr[4][2];
        #pragma unroll
        for (int n = 0; n < 4; ++n)
            #pragma unroll
            for (int kk = 0; kk < 2; ++kk)
                bfr[n][kk] = *(const bf16x8*)&sB[(wn*64 + n*16 + lr)*64 + ((kk*32 + lg*8) ^ xsw)];
        #pragma unroll
        for (int m = 0; m < 4; ++m) {
            bf16x8 af[2];
            #pragma unroll
            for (int kk = 0; kk < 2; ++kk)
                af[kk] = *(const bf16x8*)&sA[(wm*64 + m*16 + lr)*64 + ((kk*32 + lg*8) ^ xsw)];
            __builtin_amdgcn_s_setprio(1);
            #pragma unroll
            for (int n = 0; n < 4; ++n)
                #pragma unroll
                for (int kk = 0; kk < 2; ++kk)
                    acc[m][n] = __builtin_amdgcn_mfma_f32_16x16x32_bf16(af[kk], bfr[n][kk], acc[m][n], 0, 0, 0);
            __builtin_amdgcn_s_setprio(0);
        }
        if (t + 2 < KT) { VMCNT(6); }
        else            { VMCNT(0); }
        __builtin_amdgcn_s_barrier();
        __builtin_amdgcn_sched_barrier(0);
        char* tmp = s0; s0 = s1; s1 = s2; s2 = tmp;
    }

    // ---------------- fused epilogue: full tile -> LDS [256][133] f32
    __syncthreads();
    float* C = (float*)smem;
    #pragma unroll
    for (int m = 0; m < 4; ++m)
        #pragma unroll
        for (int n = 0; n < 4; ++n)
            #pragma unroll
            for (int r = 0; r < 4; ++r)
                C[(wm*64 + m*16 + lg*4 + r)*133 + wn*64 + n*16 + lr] = acc[m][n][r];
    __syncthreads();

    const int htyp = n0 >> 7;                      // 0..23
    if (htyp < 16) {
        // ---- q/k head: RMSNorm over 128 dims + RoPE; lane owns d=lane, d=lane+64
        const bool isQ = (htyp < 8);
        const int h = htyp & 7;
        unsigned short* out = isQ ? qa : ka;
        const float smul = isQ ? (ATTN_SCALE * 1.44269504088896f) : 1.0f;
        for (int rr = 0; rr < 32; ++rr) {
            int row = w*32 + rr;
            int token = m0 + row;
            int t = token & (T_SEQ-1), b = token >> 11;
            float v1 = C[row*133 + lane];
            float v2 = C[row*133 + lane + 64];
            float s = v1*v1 + v2*v2;
            #pragma unroll
            for (int mm = 1; mm < 64; mm <<= 1) s += __shfl_xor(s, mm);
            float sc2 = rsqrtf(s * (1.0f/128.0f) + RMS_EPS) * smul;
            v1 *= sc2; v2 *= sc2;
            float cs = 1.0f, sn = 0.0f;
            if (lane < 32) { float2 cc = tab[t*32 + lane]; cs = cc.x; sn = cc.y; }
            float y1 =  v1*cs + v2*sn;
            float y2 = -v1*sn + v2*cs;
            size_t ob = ((size_t)(b*NH + h) * T_SEQ + t) * HD;
            out[ob + lane]      = f2bf(y1);
            out[ob + lane + 64] = f2bf(y2);
        }
    } else {
        // ---- v head: lambda-mix with ve (row-major, coalesced), then LDS transpose -> vt [bh][d][t]
        const int h = htyp - 16;
        const float l0 = lam[0], l1 = lam[1];
        for (int rr = 0; rr < 32; ++rr) {
            int row = w*32 + rr;
            size_t token = (size_t)(m0 + row);
            float e1 = ve[token*DIM + h*HD + lane];
            float e2 = ve[token*DIM + h*HD + lane + 64];
            C[row*133 + lane]      = l0 * C[row*133 + lane]      + l1*e1;
            C[row*133 + lane + 64] = l0 * C[row*133 + lane + 64] + l1*e2;
        }
        __syncthreads();
        const int b = m0 >> 11, t0 = m0 & (T_SEQ-1);
        for (int dd = 0; dd < 16; ++dd) {
            int d = w*16 + dd;
            float x0 = C[(lane*4+0)*133 + d];
            float x1 = C[(lane*4+1)*133 + d];
            float x2 = C[(lane*4+2)*133 + d];
            float x3 = C[(lane*4+3)*133 + d];
            uint2 o;
            o.x = f2bf(x0) | ((unsigned)f2bf(x1) << 16);
            o.y = f2bf(x2) | ((unsigned)f2bf(x3) << 16);
            *(uint2*)&vt[((size_t)(b*NH + h) * HD + d) * T_SEQ + t0 + lane*4] = o;
        }
    }
}

// ---------------------------------------------------------------- GEMM  C = A * B^T (256x128, ring-3) — c_proj
template<int OUTF32>
__global__ __launch_bounds__(512, 1) void gemm256(const unsigned short* __restrict__ A,
                                                  const unsigned short* __restrict__ B,
                                                  void* __restrict__ Cout,
                                                  int M, int N, int K, int nbn) {
    __shared__ __align__(16) char smem[147456];
    const int tid  = threadIdx.x;
    const int lane = tid & 63;
    const int w    = tid >> 6;
    const int wm   = w >> 1, wn = w & 1;
    const int lr   = lane & 15, lg = lane >> 4;
    const int xsw  = (lr & 7) << 3;

    const int chunk = gridDim.x >> 3;
    const int bid2  = (blockIdx.x & 7) * chunk + (blockIdx.x >> 3);
    const int m0 = (bid2 / nbn) * 256;
    const int n0 = (bid2 % nbn) * 128;

    const int rsub = lane >> 3;
    const int csw  = ((lane & 7) ^ rsub) << 3;

    char* s0 = smem;
    char* s1 = smem + SLOT_SZ;
    char* s2 = smem + 2*SLOT_SZ;

    auto stage = [&](int kt, char* slot) {
        const int kb = kt * 64;
        #pragma unroll
        for (int i = 0; i < 4; ++i) {
            int c = w*4 + i;
            gll16(&A[(size_t)(m0 + c*8 + rsub)*K + kb + csw], slot + c*1024);
        }
        #pragma unroll
        for (int i = 0; i < 2; ++i) {
            int c = w*2 + i;
            gll16(&B[(size_t)(n0 + c*8 + rsub)*K + kb + csw], slot + SLOT_A + c*1024);
        }
    };

    f32x4 acc[4][4] = {};
    const int KT = K / 64;

    stage(0, s0);
    stage(1, s1);
    VMCNT(6);
    __builtin_amdgcn_s_barrier();
    __builtin_amdgcn_sched_barrier(0);

    for (int t = 0; t < KT; ++t) {
        if (t + 2 < KT) stage(t + 2, s2);
        const unsigned short* sA = (const unsigned short*)s0;
        const unsigned short* sB = (const unsigned short*)(s0 + SLOT_A);
        bf16x8 bfr[4][2];
        #pragma unroll
        for (int n = 0; n < 4; ++n)
            #pragma unroll
            for (int kk = 0; kk < 2; ++kk)
                bfr[n][kk] = *(const bf16x8*)&sB[(wn*64 + n*16 + lr)*64 + ((kk*32 + lg*8) ^ xsw)];
        #pragma unroll
        for (int m = 0; m < 4; ++m) {
            bf16x8 af[2];
            #pragma unroll
            for (int kk = 0; kk < 2; ++kk)
                af[kk] = *(const bf16x8*)&sA[(wm*64 + m*16 + lr)*64 + ((kk*32 + lg*8) ^ xsw)];
            __builtin_amdgcn_s_setprio(1);
            #pragma unroll
            for (int n = 0; n < 4; ++n)
                #pragma unroll
                for (int kk = 0; kk < 2; ++kk)
                    acc[m][n] = __builtin_amdgcn_mfma_f32_16x16x32_bf16(af[kk], bfr[n][kk], acc[m][n], 0, 0, 0);
            __builtin_amdgcn_s_setprio(0);
        }
        if (t + 2 < KT) { VMCNT(6); }
        else            { VMCNT(0); }
        __builtin_amdgcn_s_barrier();
        __builtin_amdgcn_sched_barrier(0);
        char* tmp = s0; s0 = s1; s1 = s2; s2 = tmp;
    }

    __syncthreads();
    float* sc = (float*)(smem + (size_t)w * 17408);
    #pragma unroll
    for (int m = 0; m < 4; ++m)
        #pragma unroll
        for (int n = 0; n < 4; ++n)
            #pragma unroll
            for (int r = 0; r < 4; ++r)
                sc[(m*16 + lg*4 + r)*68 + n*16 + lr] = acc[m][n][r];

    if (OUTF32) {
        float* Cg = (float*)Cout;
        #pragma unroll
        for (int rnd = 0; rnd < 16; ++rnd) {
            int g = rnd*64 + lane;
            int row = g >> 4, c4 = (g & 15) * 4;
            float4 v = *(float4*)&sc[row*68 + c4];
            *(float4*)&Cg[(size_t)(m0 + wm*64 + row)*N + n0 + wn*64 + c4] = v;
        }
    } else {
        unsigned short* Cg = (unsigned short*)Cout;
        #pragma unroll
        for (int rnd = 0; rnd < 8; ++rnd) {
            int g = rnd*64 + lane;
            int row = g >> 3, c8 = (g & 7) * 8;
            float4 v0 = *(float4*)&sc[row*68 + c8];
            float4 v1 = *(float4*)&sc[row*68 + c8 + 4];
            uint4 o;
            o.x = f2bf(v0.x) | ((unsigned)f2bf(v0.y) << 16);
            o.y = f2bf(v0.z) | ((unsigned)f2bf(v0.w) << 16);
            o.z = f2bf(v1.x) | ((unsigned)f2bf(v1.y) << 16);
            o.w = f2bf(v1.z) | ((unsigned)f2bf(v1.w) << 16);
            *(uint4*)&Cg[(size_t)(m0 + wm*64 + row)*N + n0 + wn*64 + c8] = o;
        }
    }
}

// ---------------------------------------------------------------- flash attention
// paired q-tiles, max-free exp2 softmax, swapped QK^T, fused A/B region;
// pack/store split so B's exp2+cvtpk hides A's LDS write->read latency.
__global__ __launch_bounds__(256, 2) void attn_fwd(const unsigned short* __restrict__ Q,
                                                   const unsigned short* __restrict__ K,
                                                   const unsigned short* __restrict__ Vt,
                                                   unsigned short* __restrict__ Y) {
    __shared__ unsigned short lK[2][64*128];   // [k][d], XOR-swizzled
    __shared__ unsigned short lV[2][128*64];   // [d][k], XOR-swizzled
    __shared__ unsigned short lP[4][16*72];    // per-wave [q][k], stride-72 pad
    __shared__ float lden[4][2][16];

    const int tid  = threadIdx.x;
    const int lane = tid & 63;
    const int w    = tid >> 6;
    const int lr   = lane & 15, lg = lane >> 4;

    const int lin = blockIdx.y * 16 + blockIdx.x;       // 0..511
    const int bh  = (lin & 7)*4 + ((lin >> 3) & 3);
    const int p   = lin >> 5;                           // 0..15
    const int qtA = p, qtB = 31 - p;

    const unsigned short* Qg = Q  + (size_t)bh * T_SEQ * HD;
    const unsigned short* Kg = K  + (size_t)bh * T_SEQ * HD;
    const unsigned short* Vg = Vt + (size_t)bh * HD * T_SEQ;
    const int q0A = qtA*64 + w*16;
    const int q0B = qtB*64 + w*16;

    auto stage = [&](int kt, int s) {
        const int kbase = kt * 64;
        #pragma unroll
        for (int i = 0; i < 4; ++i) {
            int c = w*4 + i;
            int row = c*4 + (lane >> 4);
            int col = ((lane & 15) << 3) ^ ((row & 7) << 3);
            gll16(&Kg[(size_t)(kbase + row)*HD + col], &lK[s][c*512]);
        }
        #pragma unroll
        for (int i = 0; i < 4; ++i) {
            int c = w*4 + i;
            int row = c*8 + (lane >> 3);
            int col = ((lane & 7) << 3) ^ ((row & 7) << 3);
            gll16(&Vg[(size_t)row*T_SEQ + kbase + col], &lV[s][c*512]);
        }
    };

    bf16x8 qfA[4], qfB[4];
    #pragma unroll
    for (int kk = 0; kk < 4; ++kk) {
        qfA[kk] = *(const bf16x8*)&Qg[(size_t)(q0A + lr)*HD + kk*32 + lg*8];
        qfB[kk] = *(const bf16x8*)&Qg[(size_t)(q0B + lr)*HD + kk*32 + lg*8];
    }
    VMCNT(0);
    #pragma unroll
    for (int kk = 0; kk < 4; ++kk)
        asm volatile("" :: "v"(qfA[kk]), "v"(qfB[kk]));

    f32x4 oA[8] = {}, oB[8] = {};
    float psA = 0.f, psB = 0.f;

    // helpers ------------------------------------------------------------
    auto softmax_pack = [&](f32x4* sf, float& ps, uint2* pk) {
        #pragma unroll
        for (int j = 0; j < 4; ++j)
            #pragma unroll
            for (int r = 0; r < 4; ++r) {
                float pp = exp2f(sf[j][r]);
                sf[j][r] = pp;
                ps += pp;
            }
        #pragma unroll
        for (int j = 0; j < 4; ++j) {
            pk[j].x = cvtpk(sf[j][0], sf[j][1]);
            pk[j].y = cvtpk(sf[j][2], sf[j][3]);
        }
    };
    auto p_store = [&](uint2* pk) {
        #pragma unroll
        for (int j = 0; j < 4; ++j)
            *(uint2*)&lP[w][lr*72 + j*16 + lg*4] = pk[j];
        asm volatile("" ::: "memory");
    };

    // fused A+B pass (kt <= qtA < qtB)
    auto passAB = [&](bool diagA, int kbase,
                      const unsigned short* lKc, const unsigned short* lVc) {
        f32x4 sfA[4], sfB[4];
        __builtin_amdgcn_s_setprio(1);
        #pragma unroll
        for (int j = 0; j < 4; ++j) {
            f32x4 sA = {0.f,0.f,0.f,0.f}, sB = {0.f,0.f,0.f,0.f};
            #pragma unroll
            for (int kk = 0; kk < 4; ++kk) {
                bf16x8 kf = *(const bf16x8*)&lKc[(j*16+lr)*128 + ((kk*32 + lg*8) ^ ((lr&7)<<3))];
                sA = __builtin_amdgcn_mfma_f32_16x16x32_bf16(kf, qfA[kk], sA, 0, 0, 0);
                sB = __builtin_amdgcn_mfma_f32_16x16x32_bf16(kf, qfB[kk], sB, 0, 0, 0);
            }
            sfA[j] = sA; sfB[j] = sB;
        }
        __builtin_amdgcn_s_setprio(0);
        if (diagA) {
            #pragma unroll
            for (int j = 0; j < 4; ++j)
                #pragma unroll
                for (int r = 0; r < 4; ++r) {
                    int kcol = kbase + j*16 + lg*4 + r;
                    int qrow = q0A + lr;
                    if (kcol > qrow) sfA[j][r] = -INFINITY;
                }
        }
        uint2 pkA[4], pkB[4];
        softmax_pack(sfA, psA, pkA);
        p_store(pkA);
        softmax_pack(sfB, psB, pkB);     // VALU hides A's write->read latency
        bf16x8 pfA[2];
        #pragma unroll
        for (int kk = 0; kk < 2; ++kk)
            pfA[kk] = *(const bf16x8*)&lP[w][lr*72 + kk*32 + lg*8];
        asm volatile("" ::: "memory");   // keep B-stores after pfA reads
        p_store(pkB);
        bf16x8 pfB[2];
        #pragma unroll
        for (int kk = 0; kk < 2; ++kk)
            pfB[kk] = *(const bf16x8*)&lP[w][lr*72 + kk*32 + lg*8];
        // fused PV: one V read feeds both accumulators
        #pragma unroll
        for (int n = 0; n < 8; ++n) {
            bf16x8 vf0 = *(const bf16x8*)&lVc[(n*16+lr)*64 + (( 0 + lg*8) ^ ((lr&7)<<3))];
            bf16x8 vf1 = *(const bf16x8*)&lVc[(n*16+lr)*64 + ((32 + lg*8) ^ ((lr&7)<<3))];
            __builtin_amdgcn_s_setprio(1);
            oA[n] = __builtin_amdgcn_mfma_f32_16x16x32_bf16(pfA[0], vf0, oA[n], 0, 0, 0);
            oB[n] = __builtin_amdgcn_mfma_f32_16x16x32_bf16(pfB[0], vf0, oB[n], 0, 0, 0);
            oA[n] = __builtin_amdgcn_mfma_f32_16x16x32_bf16(pfA[1], vf1, oA[n], 0, 0, 0);
            oB[n] = __builtin_amdgcn_mfma_f32_16x16x32_bf16(pfB[1], vf1, oB[n], 0, 0, 0);
            __builtin_amdgcn_s_setprio(0);
        }
    };

    // single pass (B-only region)
    auto pass = [&](bool diag, int kbase,
                    const unsigned short* lKc, const unsigned short* lVc) {
        f32x4 sf[4];
        __builtin_amdgcn_s_setprio(1);
        #pragma unroll
        for (int j = 0; j < 4; ++j) {
            f32x4 s = {0.f,0.f,0.f,0.f};
            #pragma unroll
            for (int kk = 0; kk < 4; ++kk) {
                bf16x8 kf = *(const bf16x8*)&lKc[(j*16+lr)*128 + ((kk*32 + lg*8) ^ ((lr&7)<<3))];
                s = __builtin_amdgcn_mfma_f32_16x16x32_bf16(kf, qfB[kk], s, 0, 0, 0);
            }
            sf[j] = s;
        }
        __builtin_amdgcn_s_setprio(0);
        if (diag) {
            #pragma unroll
            for (int j = 0; j < 4; ++j)
                #pragma unroll
                for (int r = 0; r < 4; ++r) {
                    int kcol = kbase + j*16 + lg*4 + r;
                    int qrow = q0B + lr;
                    if (kcol > qrow) sf[j][r] = -INFINITY;
                }
        }
        uint2 pk[4];
        softmax_pack(sf, psB, pk);
        p_store(pk);
        bf16x8 pf[2];
        #pragma unroll
        for (int kk = 0; kk < 2; ++kk)
            pf[kk] = *(const bf16x8*)&lP[w][lr*72 + kk*32 + lg*8];
        #pragma unroll
        for (int n = 0; n < 8; ++n) {
            bf16x8 vf0 = *(const bf16x8*)&lVc[(n*16+lr)*64 + (( 0 + lg*8) ^ ((lr&7)<<3))];
            bf16x8 vf1 = *(const bf16x8*)&lVc[(n*16+lr)*64 + ((32 + lg*8) ^ ((lr&7)<<3))];
            __builtin_amdgcn_s_setprio(1);
            oB[n] = __builtin_amdgcn_mfma_f32_16x16x32_bf16(pf[0], vf0, oB[n], 0, 0, 0);
            oB[n] = __builtin_amdgcn_mfma_f32_16x16x32_bf16(pf[1], vf1, oB[n], 0, 0, 0);
            __builtin_amdgcn_s_setprio(0);
        }
    };

    stage(0, 0);
    for (int kt = 0; kt <= qtB; ++kt) {
        __builtin_amdgcn_s_barrier();
        const bool pre = (kt + 1 <= qtB);
        if (pre) stage(kt + 1, (kt + 1) & 1);
        if (pre) { VMCNT(8); } else { VMCNT(0); }
        __builtin_amdgcn_sched_barrier(0);
        const int kbase = kt * 64;
        const unsigned short* lKc = lK[kt & 1];
        const unsigned short* lVc = lV[kt & 1];
        if (kt <= qtA) passAB(kt == qtA, kbase, lKc, lVc);
        else           pass(kt == qtB, kbase, lKc, lVc);
    }

    // row-sum broadcast: lane with lr=q holds partial; reduce over lg groups
    psA += __shfl_xor(psA, 16); psA += __shfl_xor(psA, 32);
    psB += __shfl_xor(psB, 16); psB += __shfl_xor(psB, 32);
    if (lane < 16) { lden[w][0][lane] = psA; lden[w][1][lane] = psB; }
    asm volatile("" ::: "memory");
    float riA[4], riB[4];
    #pragma unroll
    for (int r = 0; r < 4; ++r) {
        riA[r] = 1.0f / lden[w][0][lg*4 + r];
        riB[r] = 1.0f / lden[w][1][lg*4 + r];
    }

    const int b = bh >> 3, h = bh & 7;
    #pragma unroll
    for (int n = 0; n < 8; ++n)
        #pragma unroll
        for (int r = 0; r < 4; ++r) {
            int d = n*16 + lr;
            int qrowA = q0A + lg*4 + r;
            int qrowB = q0B + lg*4 + r;
            Y[((size_t)(b*T_SEQ + qrowA))*DIM + h*HD + d] = f2bf(oA[n][r] * riA[r]);
            Y[((size_t)(b*T_SEQ + qrowB))*DIM + h*HD + d] = f2bf(oB[n][r] * riB[r]);
        }
}

// ---------------------------------------------------------------- launch
extern "C" void kernel_launch(void* const* d_in, const int* in_sizes, int n_in,
                              void* d_out, int out_size, void* d_ws, size_t ws_size,
                              hipStream_t stream) {
    const float* x      = (const float*)d_in[0];
    const float* ve     = (const float*)d_in[1];
    const float* lam    = (const float*)d_in[2];
    const float* qkvw   = (const float*)d_in[3];
    const float* cprojw = (const float*)d_in[4];

    char* ws = (char*)d_ws;
    unsigned short* xb  = (unsigned short*)(ws);                 // 8192x1024 bf16
    unsigned short* wqb = (unsigned short*)(ws + 16777216);      // 3072x1024
    unsigned short* cpb = (unsigned short*)(ws + 23068672);      // 1024x1024
    unsigned short* qa  = (unsigned short*)(ws + 75497472);      // [bh][t][d]
    unsigned short* ka  = (unsigned short*)(ws + 92274688);      // [bh][t][d]
    unsigned short* vt  = (unsigned short*)(ws + 109051904);     // [bh][d][t]
    unsigned short* ya  = (unsigned short*)(ws + 125829120);     // 8192x1024
    float2* tab = (float2*)(ws + 142606336);                     // 512 KB RoPE table

    prep<<<12544, 256, 0, stream>>>(x, qkvw, cprojw, xb, wqb, cpb, tab);

    gemm_qkv<<<768, 512, 0, stream>>>(xb, wqb, ve, lam, tab, qa, ka, vt,
                                      NTOK, QKV_N, DIM, 24);
    attn_fwd<<<dim3(16, 32), 256, 0, stream>>>(qa, ka, vt, ya);
    gemm256<1><<<256, 512, 0, stream>>>(ya, cpb, (float*)d_out, NTOK, DIM, DIM, 8);
}

// Round 9
// 197.111 us; speedup vs baseline: 1.0124x; 1.0124x over previous
//
#include <hip/hip_runtime.h>

#define DIM 1024
#define NH 8
#define HD 128
#define T_SEQ 2048
#define NTOK 8192
#define QKV_N 3072
#define ATTN_SCALE 0.12f
#define RMS_EPS 1.1920929e-07f

using f32x4  = __attribute__((ext_vector_type(4))) float;
using bf16x8 = __attribute__((ext_vector_type(8))) __bf16;

__device__ __forceinline__ unsigned short f2bf(float f) {
    unsigned int u = __builtin_bit_cast(unsigned int, f);
    u += 0x7fffu + ((u >> 16) & 1u);           // RNE
    return (unsigned short)(u >> 16);
}
__device__ __forceinline__ float bf2f(unsigned short s) {
    unsigned int u = ((unsigned int)s) << 16;
    return __builtin_bit_cast(float, u);
}
__device__ __forceinline__ unsigned int cvtpk(float lo, float hi) {
    unsigned int r;
    asm("v_cvt_pk_bf16_f32 %0, %1, %2" : "=v"(r) : "v"(lo), "v"(hi));
    return r;
}

// async global->LDS, 16B/lane; LDS dest = wave-uniform base + lane*16 (HW)
__device__ __forceinline__ void gll16(const void* g, void* l) {
    __builtin_amdgcn_global_load_lds(
        (const __attribute__((address_space(1))) unsigned int*)g,
        (__attribute__((address_space(3))) unsigned int*)l, 16, 0, 0);
}

#define VMCNT(n) asm volatile("s_waitcnt vmcnt(" #n ")" ::: "memory")

// ---------------------------------------------------------------- prep: all f32->bf16 conversions + RoPE table, one launch
__global__ __launch_bounds__(256) void prep(const float* __restrict__ x,
                                            const float* __restrict__ qkvw,
                                            const float* __restrict__ cprojw,
                                            unsigned short* __restrict__ xb,
                                            unsigned short* __restrict__ wqb,
                                            unsigned short* __restrict__ cpb,
                                            float2* __restrict__ tab) {
    const int bid = blockIdx.x;
    const int tid = threadIdx.x;
    if (bid < 12288) {
        const float* in;
        unsigned short* out;
        int i;
        if (bid < 8192)        { in = x;      out = xb;  i = bid*256 + tid; }
        else if (bid < 11264)  { in = qkvw;   out = wqb; i = (bid-8192)*256 + tid; }
        else                   { in = cprojw; out = cpb; i = (bid-11264)*256 + tid; }
        float4 f = ((const float4*)in)[i];
        ushort4 o;
        o.x = f2bf(f.x); o.y = f2bf(f.y); o.z = f2bf(f.z); o.w = f2bf(f.w);
        ((ushort4*)out)[i] = o;
    } else {
        int idx = (bid - 12288)*256 + tid;    // < 65536
        int t = idx >> 5, i = idx & 31;
        float th = (float)t * exp2f((float)i * (-10.0f/31.0f));
        float sn, cs;
        sincosf(th, &sn, &cs);
        tab[idx] = make_float2(cs, sn);
    }
}

// ---------------------------------------------------------------- GEMM  C = A * B^T (256x128, ring-3)
#define SLOT_A 32768
#define SLOT_SZ 49152

template<int OUTF32>
__global__ __launch_bounds__(512, 1) void gemm256(const unsigned short* __restrict__ A,
                                                  const unsigned short* __restrict__ B,
                                                  void* __restrict__ Cout,
                                                  int M, int N, int K, int nbn) {
    __shared__ __align__(16) char smem[147456];
    const int tid  = threadIdx.x;
    const int lane = tid & 63;
    const int w    = tid >> 6;
    const int wm   = w >> 1, wn = w & 1;
    const int lr   = lane & 15, lg = lane >> 4;
    const int xsw  = (lr & 7) << 3;

    const int chunk = gridDim.x >> 3;
    const int bid2  = (blockIdx.x & 7) * chunk + (blockIdx.x >> 3);
    const int m0 = (bid2 / nbn) * 256;
    const int n0 = (bid2 % nbn) * 128;

    const int rsub = lane >> 3;
    const int csw  = ((lane & 7) ^ rsub) << 3;

    char* s0 = smem;
    char* s1 = smem + SLOT_SZ;
    char* s2 = smem + 2*SLOT_SZ;

    auto stage = [&](int kt, char* slot) {
        const int kb = kt * 64;
        #pragma unroll
        for (int i = 0; i < 4; ++i) {
            int c = w*4 + i;
            gll16(&A[(size_t)(m0 + c*8 + rsub)*K + kb + csw], slot + c*1024);
        }
        #pragma unroll
        for (int i = 0; i < 2; ++i) {
            int c = w*2 + i;
            gll16(&B[(size_t)(n0 + c*8 + rsub)*K + kb + csw], slot + SLOT_A + c*1024);
        }
    };

    f32x4 acc[4][4] = {};
    const int KT = K / 64;

    stage(0, s0);
    stage(1, s1);
    VMCNT(6);
    __builtin_amdgcn_s_barrier();
    __builtin_amdgcn_sched_barrier(0);

    for (int t = 0; t < KT; ++t) {
        if (t + 2 < KT) stage(t + 2, s2);
        const unsigned short* sA = (const unsigned short*)s0;
        const unsigned short* sB = (const unsigned short*)(s0 + SLOT_A);
        bf16x8 bfr[4][2];
        #pragma unroll
        for (int n = 0; n < 4; ++n)
            #pragma unroll
            for (int kk = 0; kk < 2; ++kk)
                bfr[n][kk] = *(const bf16x8*)&sB[(wn*64 + n*16 + lr)*64 + ((kk*32 + lg*8) ^ xsw)];
        #pragma unroll
        for (int m = 0; m < 4; ++m) {
            bf16x8 af[2];
            #pragma unroll
            for (int kk = 0; kk < 2; ++kk)
                af[kk] = *(const bf16x8*)&sA[(wm*64 + m*16 + lr)*64 + ((kk*32 + lg*8) ^ xsw)];
            __builtin_amdgcn_s_setprio(1);
            #pragma unroll
            for (int n = 0; n < 4; ++n)
                #pragma unroll
                for (int kk = 0; kk < 2; ++kk)
                    acc[m][n] = __builtin_amdgcn_mfma_f32_16x16x32_bf16(af[kk], bfr[n][kk], acc[m][n], 0, 0, 0);
            __builtin_amdgcn_s_setprio(0);
        }
        if (t + 2 < KT) { VMCNT(6); }
        else            { VMCNT(0); }
        __builtin_amdgcn_s_barrier();
        __builtin_amdgcn_sched_barrier(0);
        char* tmp = s0; s0 = s1; s1 = s2; s2 = tmp;
    }

    __syncthreads();
    float* sc = (float*)(smem + (size_t)w * 17408);
    #pragma unroll
    for (int m = 0; m < 4; ++m)
        #pragma unroll
        for (int n = 0; n < 4; ++n)
            #pragma unroll
            for (int r = 0; r < 4; ++r)
                sc[(m*16 + lg*4 + r)*68 + n*16 + lr] = acc[m][n][r];

    if (OUTF32) {
        float* Cg = (float*)Cout;
        #pragma unroll
        for (int rnd = 0; rnd < 16; ++rnd) {
            int g = rnd*64 + lane;
            int row = g >> 4, c4 = (g & 15) * 4;
            float4 v = *(float4*)&sc[row*68 + c4];
            *(float4*)&Cg[(size_t)(m0 + wm*64 + row)*N + n0 + wn*64 + c4] = v;
        }
    } else {
        unsigned short* Cg = (unsigned short*)Cout;
        #pragma unroll
        for (int rnd = 0; rnd < 8; ++rnd) {
            int g = rnd*64 + lane;
            int row = g >> 3, c8 = (g & 7) * 8;
            float4 v0 = *(float4*)&sc[row*68 + c8];
            float4 v1 = *(float4*)&sc[row*68 + c8 + 4];
            uint4 o;
            o.x = f2bf(v0.x) | ((unsigned)f2bf(v0.y) << 16);
            o.y = f2bf(v0.z) | ((unsigned)f2bf(v0.w) << 16);
            o.z = f2bf(v1.x) | ((unsigned)f2bf(v1.y) << 16);
            o.w = f2bf(v1.z) | ((unsigned)f2bf(v1.w) << 16);
            *(uint4*)&Cg[(size_t)(m0 + wm*64 + row)*N + n0 + wn*64 + c8] = o;
        }
    }
}

// ---------------------------------------------------------------- post: K RMSNorm+RoPE  +  v-mix+transpose (merged)
__global__ __launch_bounds__(256) void post(const unsigned short* __restrict__ qkv,
                                            const float* __restrict__ ve,
                                            const float* __restrict__ lam,
                                            const float2* __restrict__ tab,
                                            unsigned short* __restrict__ kO,
                                            unsigned short* __restrict__ vt) {
    __shared__ unsigned short lT[128*72];
    const int bid = blockIdx.x;
    const int tid = threadIdx.x;
    if (bid < 16384) {
        // ---- K: one wave per (token, head)
        int gw   = (bid*256 + tid) >> 6;
        int lane = tid & 63;
        int h     = gw & 7;
        int token = gw >> 3;
        int t     = token & (T_SEQ-1);
        int b     = token >> 11;
        const unsigned short* base = qkv + (size_t)token * QKV_N + 1024 + h*HD;
        float k1 = bf2f(base[lane]), k2 = bf2f(base[lane+64]);
        float sk = k1*k1 + k2*k2;
        #pragma unroll
        for (int m = 1; m < 64; m <<= 1) sk += __shfl_xor(sk, m);
        float ks = rsqrtf(sk * (1.0f/128.0f) + RMS_EPS);
        k1 *= ks; k2 *= ks;
        float cs = 1.0f, sn = 0.0f;
        if (lane < 32) { float2 cc = tab[t*32 + lane]; cs = cc.x; sn = cc.y; }
        float ky1 =  k1*cs + k2*sn, ky2 = -k1*sn + k2*cs;
        size_t obase = ((size_t)(b*NH + h) * T_SEQ + t) * HD;
        kO[obase + lane]      = f2bf(ky1);
        kO[obase + lane + 64] = f2bf(ky2);
    } else {
        // ---- v-mix + transpose: idx -> (t-tile, bh)
        const int idx = bid - 16384;           // 0..1023
        const int t0  = (idx & 31) * 64;
        const int bh  = idx >> 5;
        const int b = bh >> 3, h = bh & 7;
        const float l0 = lam[0], l1 = lam[1];
        #pragma unroll
        for (int it = 0; it < 4; ++it) {
            int g  = it*256 + tid;
            int t  = g >> 4;
            int d8 = (g & 15) << 3;
            size_t token = (size_t)b*T_SEQ + t0 + t;
            ushort4 v0 = *(const ushort4*)&qkv[token*QKV_N + 2048 + h*HD + d8];
            ushort4 v1 = *(const ushort4*)&qkv[token*QKV_N + 2048 + h*HD + d8 + 4];
            float4 e0 = *(const float4*)&ve[token*DIM + h*HD + d8];
            float4 e1 = *(const float4*)&ve[token*DIM + h*HD + d8 + 4];
            lT[(d8+0)*72 + t] = f2bf(l0*bf2f(v0.x) + l1*e0.x);
            lT[(d8+1)*72 + t] = f2bf(l0*bf2f(v0.y) + l1*e0.y);
            lT[(d8+2)*72 + t] = f2bf(l0*bf2f(v0.z) + l1*e0.z);
            lT[(d8+3)*72 + t] = f2bf(l0*bf2f(v0.w) + l1*e0.w);
            lT[(d8+4)*72 + t] = f2bf(l0*bf2f(v1.x) + l1*e1.x);
            lT[(d8+5)*72 + t] = f2bf(l0*bf2f(v1.y) + l1*e1.y);
            lT[(d8+6)*72 + t] = f2bf(l0*bf2f(v1.z) + l1*e1.z);
            lT[(d8+7)*72 + t] = f2bf(l0*bf2f(v1.w) + l1*e1.w);
        }
        __syncthreads();
        #pragma unroll
        for (int it = 0; it < 4; ++it) {
            int g  = it*256 + tid;
            int d  = g >> 3;
            int t8 = (g & 7) << 3;
            uint4 pk = *(const uint4*)&lT[d*72 + t8];
            *(uint4*)&vt[((size_t)bh*HD + d)*T_SEQ + t0 + t8] = pk;
        }
    }
}

// ---------------------------------------------------------------- flash attention
// Q RMSNorm+RoPE fused into the register prologue (reads raw qkv);
// paired q-tiles, max-free exp2 softmax, swapped QK^T, fused A/B region.
__global__ __launch_bounds__(256, 2) void attn_fwd(const unsigned short* __restrict__ qkv,
                                                   const unsigned short* __restrict__ K,
                                                   const unsigned short* __restrict__ Vt,
                                                   const float2* __restrict__ tab,
                                                   unsigned short* __restrict__ Y) {
    __shared__ unsigned short lK[2][64*128];   // [k][d], XOR-swizzled
    __shared__ unsigned short lV[2][128*64];   // [d][k], XOR-swizzled
    __shared__ unsigned short lP[4][16*72];    // per-wave [q][k], stride-72 pad
    __shared__ float lden[4][2][16];

    const int tid  = threadIdx.x;
    const int lane = tid & 63;
    const int w    = tid >> 6;
    const int lr   = lane & 15, lg = lane >> 4;

    const int lin = blockIdx.y * 16 + blockIdx.x;       // 0..511
    const int bh  = (lin & 7)*4 + ((lin >> 3) & 3);
    const int p   = lin >> 5;                           // 0..15
    const int qtA = p, qtB = 31 - p;
    const int b = bh >> 3, h = bh & 7;

    const unsigned short* Kg = K  + (size_t)bh * T_SEQ * HD;
    const unsigned short* Vg = Vt + (size_t)bh * HD * T_SEQ;
    const int q0A = qtA*64 + w*16;
    const int q0B = qtB*64 + w*16;

    auto stage = [&](int kt, int s) {
        const int kbase = kt * 64;
        #pragma unroll
        for (int i = 0; i < 4; ++i) {
            int c = w*4 + i;
            int row = c*4 + (lane >> 4);
            int col = ((lane & 15) << 3) ^ ((row & 7) << 3);
            gll16(&Kg[(size_t)(kbase + row)*HD + col], &lK[s][c*512]);
        }
        #pragma unroll
        for (int i = 0; i < 4; ++i) {
            int c = w*4 + i;
            int row = c*8 + (lane >> 3);
            int col = ((lane & 7) << 3) ^ ((row & 7) << 3);
            gll16(&Vg[(size_t)row*T_SEQ + kbase + col], &lV[s][c*512]);
        }
    };

    // ---- Q prologue: load raw q from qkv, RMSNorm + RoPE in registers.
    // Lane owns q-row lr, dims kk*32+lg*8+e. RoPE pair (d,d+64) = frags (kk,kk+2);
    // frag0 dims <32 (table), frag1 dims 32..63 (identity).
    auto loadQ = [&](int q0, bf16x8* qf) {
        const unsigned short* qg = qkv + ((size_t)(b*T_SEQ + q0 + lr))*QKV_N + h*HD;
        float v[4][8];
        #pragma unroll
        for (int kk = 0; kk < 4; ++kk) {
            ushort4 u0 = *(const ushort4*)&qg[kk*32 + lg*8];
            ushort4 u1 = *(const ushort4*)&qg[kk*32 + lg*8 + 4];
            v[kk][0]=bf2f(u0.x); v[kk][1]=bf2f(u0.y); v[kk][2]=bf2f(u0.z); v[kk][3]=bf2f(u0.w);
            v[kk][4]=bf2f(u1.x); v[kk][5]=bf2f(u1.y); v[kk][6]=bf2f(u1.z); v[kk][7]=bf2f(u1.w);
        }
        float s = 0.f;
        #pragma unroll
        for (int kk = 0; kk < 4; ++kk)
            #pragma unroll
            for (int e = 0; e < 8; ++e) s += v[kk][e]*v[kk][e];
        s += __shfl_xor(s, 16); s += __shfl_xor(s, 32);
        float sc = rsqrtf(s * (1.0f/128.0f) + RMS_EPS) * (ATTN_SCALE * 1.44269504088896f);
        float y[4][8];
        #pragma unroll
        for (int e = 0; e < 8; ++e) {
            float2 cc = tab[(q0 + lr)*32 + lg*8 + e];
            y[0][e] = ( v[0][e]*cc.x + v[2][e]*cc.y) * sc;
            y[2][e] = (-v[0][e]*cc.y + v[2][e]*cc.x) * sc;
            y[1][e] = v[1][e] * sc;
            y[3][e] = v[3][e] * sc;
        }
        #pragma unroll
        for (int kk = 0; kk < 4; ++kk) {
            uint4 pk;
            pk.x = cvtpk(y[kk][0], y[kk][1]);
            pk.y = cvtpk(y[kk][2], y[kk][3]);
            pk.z = cvtpk(y[kk][4], y[kk][5]);
            pk.w = cvtpk(y[kk][6], y[kk][7]);
            qf[kk] = __builtin_bit_cast(bf16x8, pk);
        }
    };

    bf16x8 qfA[4], qfB[4];
    loadQ(q0A, qfA);
    loadQ(q0B, qfB);
    VMCNT(0);
    #pragma unroll
    for (int kk = 0; kk < 4; ++kk)
        asm volatile("" :: "v"(qfA[kk]), "v"(qfB[kk]));

    f32x4 oA[8] = {}, oB[8] = {};
    float psA = 0.f, psB = 0.f;

    // helpers ------------------------------------------------------------
    auto softmax_pack = [&](f32x4* sf, float& ps, uint2* pk) {
        #pragma unroll
        for (int j = 0; j < 4; ++j)
            #pragma unroll
            for (int r = 0; r < 4; ++r) {
                float pp = exp2f(sf[j][r]);
                sf[j][r] = pp;
                ps += pp;
            }
        #pragma unroll
        for (int j = 0; j < 4; ++j) {
            pk[j].x = cvtpk(sf[j][0], sf[j][1]);
            pk[j].y = cvtpk(sf[j][2], sf[j][3]);
        }
    };
    auto p_store = [&](uint2* pk) {
        #pragma unroll
        for (int j = 0; j < 4; ++j)
            *(uint2*)&lP[w][lr*72 + j*16 + lg*4] = pk[j];
        asm volatile("" ::: "memory");
    };

    // fused A+B pass (kt <= qtA < qtB)
    auto passAB = [&](bool diagA, int kbase,
                      const unsigned short* lKc, const unsigned short* lVc) {
        f32x4 sfA[4], sfB[4];
        __builtin_amdgcn_s_setprio(1);
        #pragma unroll
        for (int j = 0; j < 4; ++j) {
            f32x4 sA = {0.f,0.f,0.f,0.f}, sB = {0.f,0.f,0.f,0.f};
            #pragma unroll
            for (int kk = 0; kk < 4; ++kk) {
                bf16x8 kf = *(const bf16x8*)&lKc[(j*16+lr)*128 + ((kk*32 + lg*8) ^ ((lr&7)<<3))];
                sA = __builtin_amdgcn_mfma_f32_16x16x32_bf16(kf, qfA[kk], sA, 0, 0, 0);
                sB = __builtin_amdgcn_mfma_f32_16x16x32_bf16(kf, qfB[kk], sB, 0, 0, 0);
            }
            sfA[j] = sA; sfB[j] = sB;
        }
        __builtin_amdgcn_s_setprio(0);
        if (diagA) {
            #pragma unroll
            for (int j = 0; j < 4; ++j)
                #pragma unroll
                for (int r = 0; r < 4; ++r) {
                    int kcol = kbase + j*16 + lg*4 + r;
                    int qrow = q0A + lr;
                    if (kcol > qrow) sfA[j][r] = -INFINITY;
                }
        }
        uint2 pkA[4], pkB[4];
        softmax_pack(sfA, psA, pkA);
        p_store(pkA);
        softmax_pack(sfB, psB, pkB);     // VALU hides A's write->read latency
        bf16x8 pfA[2];
        #pragma unroll
        for (int kk = 0; kk < 2; ++kk)
            pfA[kk] = *(const bf16x8*)&lP[w][lr*72 + kk*32 + lg*8];
        asm volatile("" ::: "memory");   // keep B-stores after pfA reads
        p_store(pkB);
        bf16x8 pfB[2];
        #pragma unroll
        for (int kk = 0; kk < 2; ++kk)
            pfB[kk] = *(const bf16x8*)&lP[w][lr*72 + kk*32 + lg*8];
        // fused PV: one V read feeds both accumulators
        #pragma unroll
        for (int n = 0; n < 8; ++n) {
            bf16x8 vf0 = *(const bf16x8*)&lVc[(n*16+lr)*64 + (( 0 + lg*8) ^ ((lr&7)<<3))];
            bf16x8 vf1 = *(const bf16x8*)&lVc[(n*16+lr)*64 + ((32 + lg*8) ^ ((lr&7)<<3))];
            __builtin_amdgcn_s_setprio(1);
            oA[n] = __builtin_amdgcn_mfma_f32_16x16x32_bf16(pfA[0], vf0, oA[n], 0, 0, 0);
            oB[n] = __builtin_amdgcn_mfma_f32_16x16x32_bf16(pfB[0], vf0, oB[n], 0, 0, 0);
            oA[n] = __builtin_amdgcn_mfma_f32_16x16x32_bf16(pfA[1], vf1, oA[n], 0, 0, 0);
            oB[n] = __builtin_amdgcn_mfma_f32_16x16x32_bf16(pfB[1], vf1, oB[n], 0, 0, 0);
            __builtin_amdgcn_s_setprio(0);
        }
    };

    // single pass (B-only region)
    auto pass = [&](bool diag, int kbase,
                    const unsigned short* lKc, const unsigned short* lVc) {
        f32x4 sf[4];
        __builtin_amdgcn_s_setprio(1);
        #pragma unroll
        for (int j = 0; j < 4; ++j) {
            f32x4 s = {0.f,0.f,0.f,0.f};
            #pragma unroll
            for (int kk = 0; kk < 4; ++kk) {
                bf16x8 kf = *(const bf16x8*)&lKc[(j*16+lr)*128 + ((kk*32 + lg*8) ^ ((lr&7)<<3))];
                s = __builtin_amdgcn_mfma_f32_16x16x32_bf16(kf, qfB[kk], s, 0, 0, 0);
            }
            sf[j] = s;
        }
        __builtin_amdgcn_s_setprio(0);
        if (diag) {
            #pragma unroll
            for (int j = 0; j < 4; ++j)
                #pragma unroll
                for (int r = 0; r < 4; ++r) {
                    int kcol = kbase + j*16 + lg*4 + r;
                    int qrow = q0B + lr;
                    if (kcol > qrow) sf[j][r] = -INFINITY;
                }
        }
        uint2 pk[4];
        softmax_pack(sf, psB, pk);
        p_store(pk);
        bf16x8 pf[2];
        #pragma unroll
        for (int kk = 0; kk < 2; ++kk)
            pf[kk] = *(const bf16x8*)&lP[w][lr*72 + kk*32 + lg*8];
        #pragma unroll
        for (int n = 0; n < 8; ++n) {
            bf16x8 vf0 = *(const bf16x8*)&lVc[(n*16+lr)*64 + (( 0 + lg*8) ^ ((lr&7)<<3))];
            bf16x8 vf1 = *(const bf16x8*)&lVc[(n*16+lr)*64 + ((32 + lg*8) ^ ((lr&7)<<3))];
            __builtin_amdgcn_s_setprio(1);
            oB[n] = __builtin_amdgcn_mfma_f32_16x16x32_bf16(pf[0], vf0, oB[n], 0, 0, 0);
            oB[n] = __builtin_amdgcn_mfma_f32_16x16x32_bf16(pf[1], vf1, oB[n], 0, 0, 0);
            __builtin_amdgcn_s_setprio(0);
        }
    };

    stage(0, 0);
    for (int kt = 0; kt <= qtB; ++kt) {
        __builtin_amdgcn_s_barrier();
        const bool pre = (kt + 1 <= qtB);
        if (pre) stage(kt + 1, (kt + 1) & 1);
        if (pre) { VMCNT(8); } else { VMCNT(0); }
        __builtin_amdgcn_sched_barrier(0);
        const int kbase = kt * 64;
        const unsigned short* lKc = lK[kt & 1];
        const unsigned short* lVc = lV[kt & 1];
        if (kt <= qtA) passAB(kt == qtA, kbase, lKc, lVc);
        else           pass(kt == qtB, kbase, lKc, lVc);
    }

    // row-sum broadcast: lane with lr=q holds partial; reduce over lg groups
    psA += __shfl_xor(psA, 16); psA += __shfl_xor(psA, 32);
    psB += __shfl_xor(psB, 16); psB += __shfl_xor(psB, 32);
    if (lane < 16) { lden[w][0][lane] = psA; lden[w][1][lane] = psB; }
    asm volatile("" ::: "memory");
    float riA[4], riB[4];
    #pragma unroll
    for (int r = 0; r < 4; ++r) {
        riA[r] = 1.0f / lden[w][0][lg*4 + r];
        riB[r] = 1.0f / lden[w][1][lg*4 + r];
    }

    #pragma unroll
    for (int n = 0; n < 8; ++n)
        #pragma unroll
        for (int r = 0; r < 4; ++r) {
            int d = n*16 + lr;
            int qrowA = q0A + lg*4 + r;
            int qrowB = q0B + lg*4 + r;
            Y[((size_t)(b*T_SEQ + qrowA))*DIM + h*HD + d] = f2bf(oA[n][r] * riA[r]);
            Y[((size_t)(b*T_SEQ + qrowB))*DIM + h*HD + d] = f2bf(oB[n][r] * riB[r]);
        }
}

// ---------------------------------------------------------------- launch
extern "C" void kernel_launch(void* const* d_in, const int* in_sizes, int n_in,
                              void* d_out, int out_size, void* d_ws, size_t ws_size,
                              hipStream_t stream) {
    const float* x      = (const float*)d_in[0];
    const float* ve     = (const float*)d_in[1];
    const float* lam    = (const float*)d_in[2];
    const float* qkvw   = (const float*)d_in[3];
    const float* cprojw = (const float*)d_in[4];

    char* ws = (char*)d_ws;
    unsigned short* xb  = (unsigned short*)(ws);                 // 8192x1024 bf16
    unsigned short* wqb = (unsigned short*)(ws + 16777216);      // 3072x1024
    unsigned short* cpb = (unsigned short*)(ws + 23068672);      // 1024x1024
    unsigned short* qkv = (unsigned short*)(ws + 25165824);      // 8192x3072
    unsigned short* ka  = (unsigned short*)(ws + 92274688);      // [bh][t][d]
    unsigned short* vt  = (unsigned short*)(ws + 109051904);     // [bh][d][t]
    unsigned short* ya  = (unsigned short*)(ws + 125829120);     // 8192x1024
    float2* tab = (float2*)(ws + 142606336);                     // 512 KB RoPE table

    prep<<<12544, 256, 0, stream>>>(x, qkvw, cprojw, xb, wqb, cpb, tab);

    gemm256<0><<<768, 512, 0, stream>>>(xb, wqb, qkv, NTOK, QKV_N, DIM, 24);
    post<<<17408, 256, 0, stream>>>(qkv, ve, lam, tab, ka, vt);
    attn_fwd<<<dim3(16, 32), 256, 0, stream>>>(qkv, ka, vt, tab, ya);
    gemm256<1><<<256, 512, 0, stream>>>(ya, cpb, (float*)d_out, NTOK, DIM, DIM, 8);
}

// Round 10
// 189.708 us; speedup vs baseline: 1.0519x; 1.0390x over previous
//
#include <hip/hip_runtime.h>

#define DIM 1024
#define NH 8
#define HD 128
#define T_SEQ 2048
#define NTOK 8192
#define QKV_N 3072
#define ATTN_SCALE 0.12f
#define RMS_EPS 1.1920929e-07f

using f32x4  = __attribute__((ext_vector_type(4))) float;
using bf16x8 = __attribute__((ext_vector_type(8))) __bf16;

__device__ __forceinline__ unsigned short f2bf(float f) {
    unsigned int u = __builtin_bit_cast(unsigned int, f);
    u += 0x7fffu + ((u >> 16) & 1u);           // RNE
    return (unsigned short)(u >> 16);
}
__device__ __forceinline__ float bf2f(unsigned short s) {
    unsigned int u = ((unsigned int)s) << 16;
    return __builtin_bit_cast(float, u);
}
__device__ __forceinline__ unsigned int cvtpk(float lo, float hi) {
    unsigned int r;
    asm("v_cvt_pk_bf16_f32 %0, %1, %2" : "=v"(r) : "v"(lo), "v"(hi));
    return r;
}

// async global->LDS, 16B/lane; LDS dest = wave-uniform base + lane*16 (HW)
__device__ __forceinline__ void gll16(const void* g, void* l) {
    __builtin_amdgcn_global_load_lds(
        (const __attribute__((address_space(1))) unsigned int*)g,
        (__attribute__((address_space(3))) unsigned int*)l, 16, 0, 0);
}

#define VMCNT(n) asm volatile("s_waitcnt vmcnt(" #n ")" ::: "memory")
#define LGKM(n)  asm volatile("s_waitcnt lgkmcnt(" #n ")" ::: "memory")
#define LGKM0 do { asm volatile("s_waitcnt lgkmcnt(0)" ::: "memory"); \
                   __builtin_amdgcn_sched_barrier(0); } while(0)
#define PH_BAR __builtin_amdgcn_s_barrier()

// ---------------------------------------------------------------- prep: all f32->bf16 conversions + RoPE table, one launch
__global__ __launch_bounds__(256) void prep(const float* __restrict__ x,
                                            const float* __restrict__ qkvw,
                                            const float* __restrict__ cprojw,
                                            unsigned short* __restrict__ xb,
                                            unsigned short* __restrict__ wqb,
                                            unsigned short* __restrict__ cpb,
                                            float2* __restrict__ tab) {
    const int bid = blockIdx.x;
    const int tid = threadIdx.x;
    if (bid < 12288) {
        const float* in;
        unsigned short* out;
        int i;
        if (bid < 8192)        { in = x;      out = xb;  i = bid*256 + tid; }
        else if (bid < 11264)  { in = qkvw;   out = wqb; i = (bid-8192)*256 + tid; }
        else                   { in = cprojw; out = cpb; i = (bid-11264)*256 + tid; }
        float4 f = ((const float4*)in)[i];
        ushort4 o;
        o.x = f2bf(f.x); o.y = f2bf(f.y); o.z = f2bf(f.z); o.w = f2bf(f.w);
        ((ushort4*)out)[i] = o;
    } else {
        int idx = (bid - 12288)*256 + tid;    // < 65536
        int t = idx >> 5, i = idx & 31;
        float th = (float)t * exp2f((float)i * (-10.0f/31.0f));
        float sn, cs;
        sincosf(th, &sn, &cs);
        tab[idx] = make_float2(cs, sn);
    }
}

// ---------------------------------------------------------------- 8-phase 256x256 GEMM  C = A * B^T  (R6 best-total version)
template<int OUTF32>
__global__ __launch_bounds__(512, 2) void gemm8p(const unsigned short* __restrict__ A,
                                                 const unsigned short* __restrict__ B,
                                                 void* __restrict__ Cout,
                                                 int M, int N, int K, int nbn) {
    __shared__ __align__(16) char smem[139264];
    const int tid  = threadIdx.x;
    const int lane = tid & 63;
    const int w    = tid >> 6;
    const int wm   = w >> 2, wn = w & 3;          // 2M x 4N
    const int lr   = lane & 15, lg = lane >> 4;

    const int chunk = gridDim.x >> 3;             // grid % 8 == 0
    const int bid2  = (blockIdx.x & 7) * chunk + (blockIdx.x >> 3);
    const int bm = (bid2 / nbn) * 256;
    const int bn = (bid2 % nbn) * 256;

    const int rsub = lane >> 3;                   // 0..7
    const int csw  = ((lane & 7) ^ rsub) << 3;    // pre-swizzled source col (elems)
    const int KT = K / 64;

    auto stA = [&](int t, int h) {
        if (t >= KT) return;
        char* dst = smem + (t & 1) * 65536 + h * 16384;
        #pragma unroll
        for (int i = 0; i < 2; ++i) {
            int c = w*2 + i;
            gll16(&A[(size_t)(bm + h*128 + c*8 + rsub)*K + t*64 + csw], dst + c*1024);
        }
    };
    auto stB = [&](int t, int h) {
        if (t >= KT) return;
        char* dst = smem + (t & 1) * 65536 + 32768 + h * 16384;
        #pragma unroll
        for (int i = 0; i < 2; ++i) {
            int c = w*2 + i;
            gll16(&B[(size_t)(bn + h*128 + c*8 + rsub)*K + t*64 + csw], dst + c*1024);
        }
    };

    f32x4 acc[8][4] = {};
    bf16x8 a0[4][2], a1[4][2], bb[2][2];

    auto rdA = [&](int t, int qm, bf16x8 (*a)[2]) {
        const unsigned short* base = (const unsigned short*)(smem + (t & 1)*65536 + wm*16384);
        #pragma unroll
        for (int m = 0; m < 4; ++m) {
            int row = qm*64 + m*16 + lr;
            int sw = (row & 7) << 3;
            #pragma unroll
            for (int kk = 0; kk < 2; ++kk)
                a[m][kk] = *(const bf16x8*)&base[row*64 + ((kk*32 + lg*8) ^ sw)];
        }
    };
    auto rdB = [&](int t, int qn) {
        const unsigned short* base = (const unsigned short*)(smem + (t & 1)*65536 + 32768 + (wn >> 1)*16384);
        #pragma unroll
        for (int n = 0; n < 2; ++n) {
            int row = (wn & 1)*64 + qn*32 + n*16 + lr;
            int sw = (row & 7) << 3;
            #pragma unroll
            for (int kk = 0; kk < 2; ++kk)
                bb[n][kk] = *(const bf16x8*)&base[row*64 + ((kk*32 + lg*8) ^ sw)];
        }
    };
    auto mm = [&](bf16x8 (*a)[2], int qm, int qn) {
        __builtin_amdgcn_s_setprio(1);
        #pragma unroll
        for (int m = 0; m < 4; ++m)
            #pragma unroll
            for (int n = 0; n < 2; ++n)
                #pragma unroll
                for (int kk = 0; kk < 2; ++kk)
                    acc[qm*4+m][qn*2+n] =
                        __builtin_amdgcn_mfma_f32_16x16x32_bf16(a[m][kk], bb[n][kk],
                                                                acc[qm*4+m][qn*2+n], 0, 0, 0);
        __builtin_amdgcn_s_setprio(0);
    };

    // prologue: tile0 complete + A(1) in flight
    stA(0, 0); stA(0, 1); stB(0, 0); stB(0, 1);
    stA(1, 0); stA(1, 1);
    VMCNT(4);
    PH_BAR;

    for (int t = 0; t < KT; ++t) {
        // ph1: quadrant (0,0)
        rdA(t, 0, a0); rdB(t, 0);
        stB(t + 1, 0);
        LGKM(8);
        PH_BAR; LGKM0;
        mm(a0, 0, 0);
        PH_BAR;
        // ph2: quadrant (1,0)
        rdA(t, 1, a1);
        stB(t + 1, 1);
        PH_BAR; LGKM0;
        mm(a1, 1, 0);
        PH_BAR;
        // ph3: quadrant (0,1)
        rdB(t, 1);
        stA(t + 2, 0);
        PH_BAR; LGKM0;
        mm(a0, 0, 1);
        PH_BAR;
        // ph4: quadrant (1,1)
        stA(t + 2, 1);
        if (t + 2 < KT) { VMCNT(4); } else { VMCNT(0); }
        PH_BAR;
        mm(a1, 1, 1);
        PH_BAR;
    }

    __syncthreads();
    float* sc = (float*)(smem + (size_t)w * 17408);    // 64 x 68 f32 per wave
    #pragma unroll
    for (int f = 0; f < 2; ++f) {
        #pragma unroll
        for (int m = 0; m < 4; ++m)
            #pragma unroll
            for (int n = 0; n < 4; ++n)
                #pragma unroll
                for (int r = 0; r < 4; ++r)
                    sc[(m*16 + lg*4 + r)*68 + n*16 + lr] = acc[f*4+m][n][r];
        if (OUTF32) {
            float* C = (float*)Cout;
            #pragma unroll
            for (int rnd = 0; rnd < 16; ++rnd) {
                int g = rnd*64 + lane;
                int row = g >> 4, c4 = (g & 15) * 4;
                float4 v = *(float4*)&sc[row*68 + c4];
                *(float4*)&C[(size_t)(bm + wm*128 + f*64 + row)*N + bn + wn*64 + c4] = v;
            }
        } else {
            unsigned short* C = (unsigned short*)Cout;
            #pragma unroll
            for (int rnd = 0; rnd < 8; ++rnd) {
                int g = rnd*64 + lane;
                int row = g >> 3, c8 = (g & 7) * 8;
                float4 v0 = *(float4*)&sc[row*68 + c8];
                float4 v1 = *(float4*)&sc[row*68 + c8 + 4];
                uint4 o;
                o.x = f2bf(v0.x) | ((unsigned)f2bf(v0.y) << 16);
                o.y = f2bf(v0.z) | ((unsigned)f2bf(v0.w) << 16);
                o.z = f2bf(v1.x) | ((unsigned)f2bf(v1.y) << 16);
                o.w = f2bf(v1.z) | ((unsigned)f2bf(v1.w) << 16);
                *(uint4*)&C[(size_t)(bm + wm*128 + f*64 + row)*N + bn + wn*64 + c8] = o;
            }
        }
        if (f == 0) __syncthreads();
    }
}

// ---------------------------------------------------------------- GEMM  C = A * B^T (256x128, ring-3) — c_proj
#define SLOT_A 32768
#define SLOT_SZ 49152

template<int OUTF32>
__global__ __launch_bounds__(512, 1) void gemm256(const unsigned short* __restrict__ A,
                                                  const unsigned short* __restrict__ B,
                                                  void* __restrict__ Cout,
                                                  int M, int N, int K, int nbn) {
    __shared__ __align__(16) char smem[147456];
    const int tid  = threadIdx.x;
    const int lane = tid & 63;
    const int w    = tid >> 6;
    const int wm   = w >> 1, wn = w & 1;
    const int lr   = lane & 15, lg = lane >> 4;
    const int xsw  = (lr & 7) << 3;

    const int chunk = gridDim.x >> 3;
    const int bid2  = (blockIdx.x & 7) * chunk + (blockIdx.x >> 3);
    const int m0 = (bid2 / nbn) * 256;
    const int n0 = (bid2 % nbn) * 128;

    const int rsub = lane >> 3;
    const int csw  = ((lane & 7) ^ rsub) << 3;

    char* s0 = smem;
    char* s1 = smem + SLOT_SZ;
    char* s2 = smem + 2*SLOT_SZ;

    auto stage = [&](int kt, char* slot) {
        const int kb = kt * 64;
        #pragma unroll
        for (int i = 0; i < 4; ++i) {
            int c = w*4 + i;
            gll16(&A[(size_t)(m0 + c*8 + rsub)*K + kb + csw], slot + c*1024);
        }
        #pragma unroll
        for (int i = 0; i < 2; ++i) {
            int c = w*2 + i;
            gll16(&B[(size_t)(n0 + c*8 + rsub)*K + kb + csw], slot + SLOT_A + c*1024);
        }
    };

    f32x4 acc[4][4] = {};
    const int KT = K / 64;

    stage(0, s0);
    stage(1, s1);
    VMCNT(6);
    __builtin_amdgcn_s_barrier();
    __builtin_amdgcn_sched_barrier(0);

    for (int t = 0; t < KT; ++t) {
        if (t + 2 < KT) stage(t + 2, s2);
        const unsigned short* sA = (const unsigned short*)s0;
        const unsigned short* sB = (const unsigned short*)(s0 + SLOT_A);
        bf16x8 bfr[4][2];
        #pragma unroll
        for (int n = 0; n < 4; ++n)
            #pragma unroll
            for (int kk = 0; kk < 2; ++kk)
                bfr[n][kk] = *(const bf16x8*)&sB[(wn*64 + n*16 + lr)*64 + ((kk*32 + lg*8) ^ xsw)];
        #pragma unroll
        for (int m = 0; m < 4; ++m) {
            bf16x8 af[2];
            #pragma unroll
            for (int kk = 0; kk < 2; ++kk)
                af[kk] = *(const bf16x8*)&sA[(wm*64 + m*16 + lr)*64 + ((kk*32 + lg*8) ^ xsw)];
            __builtin_amdgcn_s_setprio(1);
            #pragma unroll
            for (int n = 0; n < 4; ++n)
                #pragma unroll
                for (int kk = 0; kk < 2; ++kk)
                    acc[m][n] = __builtin_amdgcn_mfma_f32_16x16x32_bf16(af[kk], bfr[n][kk], acc[m][n], 0, 0, 0);
            __builtin_amdgcn_s_setprio(0);
        }
        if (t + 2 < KT) { VMCNT(6); }
        else            { VMCNT(0); }
        __builtin_amdgcn_s_barrier();
        __builtin_amdgcn_sched_barrier(0);
        char* tmp = s0; s0 = s1; s1 = s2; s2 = tmp;
    }

    __syncthreads();
    float* sc = (float*)(smem + (size_t)w * 17408);
    #pragma unroll
    for (int m = 0; m < 4; ++m)
        #pragma unroll
        for (int n = 0; n < 4; ++n)
            #pragma unroll
            for (int r = 0; r < 4; ++r)
                sc[(m*16 + lg*4 + r)*68 + n*16 + lr] = acc[m][n][r];

    if (OUTF32) {
        float* Cg = (float*)Cout;
        #pragma unroll
        for (int rnd = 0; rnd < 16; ++rnd) {
            int g = rnd*64 + lane;
            int row = g >> 4, c4 = (g & 15) * 4;
            float4 v = *(float4*)&sc[row*68 + c4];
            *(float4*)&Cg[(size_t)(m0 + wm*64 + row)*N + n0 + wn*64 + c4] = v;
        }
    } else {
        unsigned short* Cg = (unsigned short*)Cout;
        #pragma unroll
        for (int rnd = 0; rnd < 8; ++rnd) {
            int g = rnd*64 + lane;
            int row = g >> 3, c8 = (g & 7) * 8;
            float4 v0 = *(float4*)&sc[row*68 + c8];
            float4 v1 = *(float4*)&sc[row*68 + c8 + 4];
            uint4 o;
            o.x = f2bf(v0.x) | ((unsigned)f2bf(v0.y) << 16);
            o.y = f2bf(v0.z) | ((unsigned)f2bf(v0.w) << 16);
            o.z = f2bf(v1.x) | ((unsigned)f2bf(v1.y) << 16);
            o.w = f2bf(v1.z) | ((unsigned)f2bf(v1.w) << 16);
            *(uint4*)&Cg[(size_t)(m0 + wm*64 + row)*N + n0 + wn*64 + c8] = o;
        }
    }
}

// ---------------------------------------------------------------- post: Q/K RMSNorm+RoPE  +  v-mix+transpose (merged)
__global__ __launch_bounds__(256) void post(const unsigned short* __restrict__ qkv,
                                            const float* __restrict__ ve,
                                            const float* __restrict__ lam,
                                            const float2* __restrict__ tab,
                                            unsigned short* __restrict__ qO,
                                            unsigned short* __restrict__ kO,
                                            unsigned short* __restrict__ vt) {
    __shared__ unsigned short lT[128*72];
    const int bid = blockIdx.x;
    const int tid = threadIdx.x;
    if (bid < 16384) {
        // ---- Q+K: one wave per (token, head)
        int gw   = (bid*256 + tid) >> 6;
        int lane = tid & 63;
        int h     = gw & 7;
        int token = gw >> 3;
        int t     = token & (T_SEQ-1);
        int b     = token >> 11;

        const unsigned short* base = qkv + (size_t)token * QKV_N + h*HD;
        float q1 = bf2f(base[lane]),        q2 = bf2f(base[lane+64]);
        float k1 = bf2f(base[1024+lane]),   k2 = bf2f(base[1024+lane+64]);

        float sq = q1*q1 + q2*q2;
        float sk = k1*k1 + k2*k2;
        #pragma unroll
        for (int m = 1; m < 64; m <<= 1) {
            sq += __shfl_xor(sq, m);
            sk += __shfl_xor(sk, m);
        }
        float qs = rsqrtf(sq * (1.0f/128.0f) + RMS_EPS) * (ATTN_SCALE * 1.44269504088896f);
        float ks = rsqrtf(sk * (1.0f/128.0f) + RMS_EPS);
        q1 *= qs; q2 *= qs; k1 *= ks; k2 *= ks;

        float cs = 1.0f, sn = 0.0f;
        if (lane < 32) { float2 cc = tab[t*32 + lane]; cs = cc.x; sn = cc.y; }
        float qy1 =  q1*cs + q2*sn, qy2 = -q1*sn + q2*cs;
        float ky1 =  k1*cs + k2*sn, ky2 = -k1*sn + k2*cs;

        size_t obase = ((size_t)(b*NH + h) * T_SEQ + t) * HD;
        qO[obase + lane]      = f2bf(qy1);
        qO[obase + lane + 64] = f2bf(qy2);
        kO[obase + lane]      = f2bf(ky1);
        kO[obase + lane + 64] = f2bf(ky2);
    } else {
        // ---- v-mix + transpose: idx -> (t-tile, bh)
        const int idx = bid - 16384;           // 0..1023
        const int t0  = (idx & 31) * 64;
        const int bh  = idx >> 5;
        const int b = bh >> 3, h = bh & 7;
        const float l0 = lam[0], l1 = lam[1];
        #pragma unroll
        for (int it = 0; it < 4; ++it) {
            int g  = it*256 + tid;
            int t  = g >> 4;
            int d8 = (g & 15) << 3;
            size_t token = (size_t)b*T_SEQ + t0 + t;
            ushort4 v0 = *(const ushort4*)&qkv[token*QKV_N + 2048 + h*HD + d8];
            ushort4 v1 = *(const ushort4*)&qkv[token*QKV_N + 2048 + h*HD + d8 + 4];
            float4 e0 = *(const float4*)&ve[token*DIM + h*HD + d8];
            float4 e1 = *(const float4*)&ve[token*DIM + h*HD + d8 + 4];
            lT[(d8+0)*72 + t] = f2bf(l0*bf2f(v0.x) + l1*e0.x);
            lT[(d8+1)*72 + t] = f2bf(l0*bf2f(v0.y) + l1*e0.y);
            lT[(d8+2)*72 + t] = f2bf(l0*bf2f(v0.z) + l1*e0.z);
            lT[(d8+3)*72 + t] = f2bf(l0*bf2f(v0.w) + l1*e0.w);
            lT[(d8+4)*72 + t] = f2bf(l0*bf2f(v1.x) + l1*e1.x);
            lT[(d8+5)*72 + t] = f2bf(l0*bf2f(v1.y) + l1*e1.y);
            lT[(d8+6)*72 + t] = f2bf(l0*bf2f(v1.z) + l1*e1.z);
            lT[(d8+7)*72 + t] = f2bf(l0*bf2f(v1.w) + l1*e1.w);
        }
        __syncthreads();
        #pragma unroll
        for (int it = 0; it < 4; ++it) {
            int g  = it*256 + tid;
            int d  = g >> 3;
            int t8 = (g & 7) << 3;
            uint4 pk = *(const uint4*)&lT[d*72 + t8];
            *(uint4*)&vt[((size_t)bh*HD + d)*T_SEQ + t0 + t8] = pk;
        }
    }
}

// ---------------------------------------------------------------- flash attention
// paired q-tiles, max-free exp2 softmax, swapped QK^T, fused A/B region;
// pack/store split so B's exp2+cvtpk hides A's LDS write->read latency.
__global__ __launch_bounds__(256, 2) void attn_fwd(const unsigned short* __restrict__ Q,
                                                   const unsigned short* __restrict__ K,
                                                   const unsigned short* __restrict__ Vt,
                                                   unsigned short* __restrict__ Y) {
    __shared__ unsigned short lK[2][64*128];   // [k][d], XOR-swizzled
    __shared__ unsigned short lV[2][128*64];   // [d][k], XOR-swizzled
    __shared__ unsigned short lP[4][16*72];    // per-wave [q][k], stride-72 pad
    __shared__ float lden[4][2][16];

    const int tid  = threadIdx.x;
    const int lane = tid & 63;
    const int w    = tid >> 6;
    const int lr   = lane & 15, lg = lane >> 4;

    const int lin = blockIdx.y * 16 + blockIdx.x;       // 0..511
    const int bh  = (lin & 7)*4 + ((lin >> 3) & 3);
    const int p   = lin >> 5;                           // 0..15
    const int qtA = p, qtB = 31 - p;

    const unsigned short* Qg = Q  + (size_t)bh * T_SEQ * HD;
    const unsigned short* Kg = K  + (size_t)bh * T_SEQ * HD;
    const unsigned short* Vg = Vt + (size_t)bh * HD * T_SEQ;
    const int q0A = qtA*64 + w*16;
    const int q0B = qtB*64 + w*16;

    auto stage = [&](int kt, int s) {
        const int kbase = kt * 64;
        #pragma unroll
        for (int i = 0; i < 4; ++i) {
            int c = w*4 + i;
            int row = c*4 + (lane >> 4);
            int col = ((lane & 15) << 3) ^ ((row & 7) << 3);
            gll16(&Kg[(size_t)(kbase + row)*HD + col], &lK[s][c*512]);
        }
        #pragma unroll
        for (int i = 0; i < 4; ++i) {
            int c = w*4 + i;
            int row = c*8 + (lane >> 3);
            int col = ((lane & 7) << 3) ^ ((row & 7) << 3);
            gll16(&Vg[(size_t)row*T_SEQ + kbase + col], &lV[s][c*512]);
        }
    };

    bf16x8 qfA[4], qfB[4];
    #pragma unroll
    for (int kk = 0; kk < 4; ++kk) {
        qfA[kk] = *(const bf16x8*)&Qg[(size_t)(q0A + lr)*HD + kk*32 + lg*8];
        qfB[kk] = *(const bf16x8*)&Qg[(size_t)(q0B + lr)*HD + kk*32 + lg*8];
    }
    VMCNT(0);
    #pragma unroll
    for (int kk = 0; kk < 4; ++kk)
        asm volatile("" :: "v"(qfA[kk]), "v"(qfB[kk]));

    f32x4 oA[8] = {}, oB[8] = {};
    float psA = 0.f, psB = 0.f;

    // helpers ------------------------------------------------------------
    auto softmax_pack = [&](f32x4* sf, float& ps, uint2* pk) {
        #pragma unroll
        for (int j = 0; j < 4; ++j)
            #pragma unroll
            for (int r = 0; r < 4; ++r) {
                float pp = exp2f(sf[j][r]);
                sf[j][r] = pp;
                ps += pp;
            }
        #pragma unroll
        for (int j = 0; j < 4; ++j) {
            pk[j].x = cvtpk(sf[j][0], sf[j][1]);
            pk[j].y = cvtpk(sf[j][2], sf[j][3]);
        }
    };
    auto p_store = [&](uint2* pk) {
        #pragma unroll
        for (int j = 0; j < 4; ++j)
            *(uint2*)&lP[w][lr*72 + j*16 + lg*4] = pk[j];
        asm volatile("" ::: "memory");
    };

    // fused A+B pass (kt <= qtA < qtB)
    auto passAB = [&](bool diagA, int kbase,
                      const unsigned short* lKc, const unsigned short* lVc) {
        f32x4 sfA[4], sfB[4];
        __builtin_amdgcn_s_setprio(1);
        #pragma unroll
        for (int j = 0; j < 4; ++j) {
            f32x4 sA = {0.f,0.f,0.f,0.f}, sB = {0.f,0.f,0.f,0.f};
            #pragma unroll
            for (int kk = 0; kk < 4; ++kk) {
                bf16x8 kf = *(const bf16x8*)&lKc[(j*16+lr)*128 + ((kk*32 + lg*8) ^ ((lr&7)<<3))];
                sA = __builtin_amdgcn_mfma_f32_16x16x32_bf16(kf, qfA[kk], sA, 0, 0, 0);
                sB = __builtin_amdgcn_mfma_f32_16x16x32_bf16(kf, qfB[kk], sB, 0, 0, 0);
            }
            sfA[j] = sA; sfB[j] = sB;
        }
        __builtin_amdgcn_s_setprio(0);
        if (diagA) {
            #pragma unroll
            for (int j = 0; j < 4; ++j)
                #pragma unroll
                for (int r = 0; r < 4; ++r) {
                    int kcol = kbase + j*16 + lg*4 + r;
                    int qrow = q0A + lr;
                    if (kcol > qrow) sfA[j][r] = -INFINITY;
                }
        }
        uint2 pkA[4], pkB[4];
        softmax_pack(sfA, psA, pkA);
        p_store(pkA);
        softmax_pack(sfB, psB, pkB);     // VALU hides A's write->read latency
        bf16x8 pfA[2];
        #pragma unroll
        for (int kk = 0; kk < 2; ++kk)
            pfA[kk] = *(const bf16x8*)&lP[w][lr*72 + kk*32 + lg*8];
        asm volatile("" ::: "memory");   // keep B-stores after pfA reads
        p_store(pkB);
        bf16x8 pfB[2];
        #pragma unroll
        for (int kk = 0; kk < 2; ++kk)
            pfB[kk] = *(const bf16x8*)&lP[w][lr*72 + kk*32 + lg*8];
        // fused PV: one V read feeds both accumulators
        #pragma unroll
        for (int n = 0; n < 8; ++n) {
            bf16x8 vf0 = *(const bf16x8*)&lVc[(n*16+lr)*64 + (( 0 + lg*8) ^ ((lr&7)<<3))];
            bf16x8 vf1 = *(const bf16x8*)&lVc[(n*16+lr)*64 + ((32 + lg*8) ^ ((lr&7)<<3))];
            __builtin_amdgcn_s_setprio(1);
            oA[n] = __builtin_amdgcn_mfma_f32_16x16x32_bf16(pfA[0], vf0, oA[n], 0, 0, 0);
            oB[n] = __builtin_amdgcn_mfma_f32_16x16x32_bf16(pfB[0], vf0, oB[n], 0, 0, 0);
            oA[n] = __builtin_amdgcn_mfma_f32_16x16x32_bf16(pfA[1], vf1, oA[n], 0, 0, 0);
            oB[n] = __builtin_amdgcn_mfma_f32_16x16x32_bf16(pfB[1], vf1, oB[n], 0, 0, 0);
            __builtin_amdgcn_s_setprio(0);
        }
    };

    // single pass (B-only region)
    auto pass = [&](bool diag, int kbase,
                    const unsigned short* lKc, const unsigned short* lVc) {
        f32x4 sf[4];
        __builtin_amdgcn_s_setprio(1);
        #pragma unroll
        for (int j = 0; j < 4; ++j) {
            f32x4 s = {0.f,0.f,0.f,0.f};
            #pragma unroll
            for (int kk = 0; kk < 4; ++kk) {
                bf16x8 kf = *(const bf16x8*)&lKc[(j*16+lr)*128 + ((kk*32 + lg*8) ^ ((lr&7)<<3))];
                s = __builtin_amdgcn_mfma_f32_16x16x32_bf16(kf, qfB[kk], s, 0, 0, 0);
            }
            sf[j] = s;
        }
        __builtin_amdgcn_s_setprio(0);
        if (diag) {
            #pragma unroll
            for (int j = 0; j < 4; ++j)
                #pragma unroll
                for (int r = 0; r < 4; ++r) {
                    int kcol = kbase + j*16 + lg*4 + r;
                    int qrow = q0B + lr;
                    if (kcol > qrow) sf[j][r] = -INFINITY;
                }
        }
        uint2 pk[4];
        softmax_pack(sf, psB, pk);
        p_store(pk);
        bf16x8 pf[2];
        #pragma unroll
        for (int kk = 0; kk < 2; ++kk)
            pf[kk] = *(const bf16x8*)&lP[w][lr*72 + kk*32 + lg*8];
        #pragma unroll
        for (int n = 0; n < 8; ++n) {
            bf16x8 vf0 = *(const bf16x8*)&lVc[(n*16+lr)*64 + (( 0 + lg*8) ^ ((lr&7)<<3))];
            bf16x8 vf1 = *(const bf16x8*)&lVc[(n*16+lr)*64 + ((32 + lg*8) ^ ((lr&7)<<3))];
            __builtin_amdgcn_s_setprio(1);
            oB[n] = __builtin_amdgcn_mfma_f32_16x16x32_bf16(pf[0], vf0, oB[n], 0, 0, 0);
            oB[n] = __builtin_amdgcn_mfma_f32_16x16x32_bf16(pf[1], vf1, oB[n], 0, 0, 0);
            __builtin_amdgcn_s_setprio(0);
        }
    };

    stage(0, 0);
    for (int kt = 0; kt <= qtB; ++kt) {
        __builtin_amdgcn_s_barrier();
        const bool pre = (kt + 1 <= qtB);
        if (pre) stage(kt + 1, (kt + 1) & 1);
        if (pre) { VMCNT(8); } else { VMCNT(0); }
        __builtin_amdgcn_sched_barrier(0);
        const int kbase = kt * 64;
        const unsigned short* lKc = lK[kt & 1];
        const unsigned short* lVc = lV[kt & 1];
        if (kt <= qtA) passAB(kt == qtA, kbase, lKc, lVc);
        else           pass(kt == qtB, kbase, lKc, lVc);
    }

    // row-sum broadcast: lane with lr=q holds partial; reduce over lg groups
    psA += __shfl_xor(psA, 16); psA += __shfl_xor(psA, 32);
    psB += __shfl_xor(psB, 16); psB += __shfl_xor(psB, 32);
    if (lane < 16) { lden[w][0][lane] = psA; lden[w][1][lane] = psB; }
    asm volatile("" ::: "memory");
    float riA[4], riB[4];
    #pragma unroll
    for (int r = 0; r < 4; ++r) {
        riA[r] = 1.0f / lden[w][0][lg*4 + r];
        riB[r] = 1.0f / lden[w][1][lg*4 + r];
    }

    const int b = bh >> 3, h = bh & 7;
    #pragma unroll
    for (int n = 0; n < 8; ++n)
        #pragma unroll
        for (int r = 0; r < 4; ++r) {
            int d = n*16 + lr;
            int qrowA = q0A + lg*4 + r;
            int qrowB = q0B + lg*4 + r;
            Y[((size_t)(b*T_SEQ + qrowA))*DIM + h*HD + d] = f2bf(oA[n][r] * riA[r]);
            Y[((size_t)(b*T_SEQ + qrowB))*DIM + h*HD + d] = f2bf(oB[n][r] * riB[r]);
        }
}

// ---------------------------------------------------------------- launch
extern "C" void kernel_launch(void* const* d_in, const int* in_sizes, int n_in,
                              void* d_out, int out_size, void* d_ws, size_t ws_size,
                              hipStream_t stream) {
    const float* x      = (const float*)d_in[0];
    const float* ve     = (const float*)d_in[1];
    const float* lam    = (const float*)d_in[2];
    const float* qkvw   = (const float*)d_in[3];
    const float* cprojw = (const float*)d_in[4];

    char* ws = (char*)d_ws;
    unsigned short* xb  = (unsigned short*)(ws);                 // 8192x1024 bf16
    unsigned short* wqb = (unsigned short*)(ws + 16777216);      // 3072x1024
    unsigned short* cpb = (unsigned short*)(ws + 23068672);      // 1024x1024
    unsigned short* qkv = (unsigned short*)(ws + 25165824);      // 8192x3072
    unsigned short* qa  = (unsigned short*)(ws + 75497472);      // [bh][t][d]
    unsigned short* ka  = (unsigned short*)(ws + 92274688);      // [bh][t][d]
    unsigned short* vt  = (unsigned short*)(ws + 109051904);     // [bh][d][t]
    unsigned short* ya  = (unsigned short*)(ws + 125829120);     // 8192x1024
    float2* tab = (float2*)(ws + 142606336);                     // 512 KB RoPE table

    prep<<<12544, 256, 0, stream>>>(x, qkvw, cprojw, xb, wqb, cpb, tab);

    gemm8p<0><<<384, 512, 0, stream>>>(xb, wqb, qkv, NTOK, QKV_N, DIM, 12);
    post<<<17408, 256, 0, stream>>>(qkv, ve, lam, tab, qa, ka, vt);
    attn_fwd<<<dim3(16, 32), 256, 0, stream>>>(qa, ka, vt, ya);
    gemm256<1><<<256, 512, 0, stream>>>(ya, cpb, (float*)d_out, NTOK, DIM, DIM, 8);
}